// Round 2
// baseline (4827.342 us; speedup 1.0000x reference)
//
#include <hip/hip_runtime.h>
#include <cmath>

#define HID 64
#define IN_C 128

__device__ __forceinline__ float rl(float v, int k) {
    return __uint_as_float(__builtin_amdgcn_readlane(__float_as_uint(v), k));
}

// ---- CSR build ----------------------------------------------------------

__global__ void k_hist(const int* __restrict__ dst, int* __restrict__ counts, int E) {
    int e = blockIdx.x * blockDim.x + threadIdx.x;
    if (e < E) atomicAdd(&counts[dst[e]], 1);
}

__global__ void k_scan_block(const int* __restrict__ counts, int* __restrict__ row_ptr,
                             int* __restrict__ chunk_sums, int n) {
    __shared__ int s[1024];
    int i = blockIdx.x * 1024 + threadIdx.x;
    int v = (i < n) ? counts[i] : 0;
    s[threadIdx.x] = v;
    __syncthreads();
    for (int off = 1; off < 1024; off <<= 1) {
        int t = (threadIdx.x >= off) ? s[threadIdx.x - off] : 0;
        __syncthreads();
        s[threadIdx.x] += t;
        __syncthreads();
    }
    if (i < n) row_ptr[i] = s[threadIdx.x] - v;   // exclusive
    if (threadIdx.x == 1023) chunk_sums[blockIdx.x] = s[1023];
}

__global__ void k_scan_fix(int* __restrict__ row_ptr, const int* __restrict__ chunk_sums,
                           int n, int total) {
    __shared__ int base_s;
    if (threadIdx.x == 0) {
        int b = 0;
        for (int c = 0; c < (int)blockIdx.x; ++c) b += chunk_sums[c];
        base_s = b;
    }
    __syncthreads();
    int i = blockIdx.x * 1024 + threadIdx.x;
    if (i < n) row_ptr[i] += base_s;
    if (i == 0) row_ptr[n] = total;
}

__global__ void k_fill(const int* __restrict__ src, const int* __restrict__ dst,
                       const int* __restrict__ row_ptr, int* __restrict__ cursor,
                       int* __restrict__ col_idx, int E) {
    int e = blockIdx.x * blockDim.x + threadIdx.x;
    if (e < E) {
        int d = dst[e];
        int pos = row_ptr[d] + atomicAdd(&cursor[d], 1);
        col_idx[pos] = src[e];
    }
}

// ---- input projection: h0 = relu(x @ lin0_w^T + b) ----------------------
// W^T staged in LDS (pad 65 keeps staging writes and reads conflict-free).
// 2 nodes per wave iteration for ILP.
__global__ __launch_bounds__(256) void k_lin0(const float* __restrict__ x,
                                              const float* __restrict__ w,
                                              const float* __restrict__ b,
                                              float* __restrict__ h0, int N) {
    __shared__ float Wt[IN_C * 65];
    for (int i = threadIdx.x; i < IN_C * HID; i += 256) {
        int o = i >> 7, k = i & 127;              // w[o][k]
        Wt[k * 65 + o] = w[i];
    }
    __syncthreads();
    int lane = threadIdx.x & 63;
    int wid = (blockIdx.x * blockDim.x + threadIdx.x) >> 6;
    int nw = (gridDim.x * blockDim.x) >> 6;
    float bias = b[lane];
    for (int n0 = wid; n0 < N; n0 += 2 * nw) {
        int n1 = n0 + nw;
        bool v1 = n1 < N;
        int n1c = v1 ? n1 : n0;
        float xa0 = x[(size_t)n0 * IN_C + lane];
        float xa1 = x[(size_t)n0 * IN_C + 64 + lane];
        float xb0 = x[(size_t)n1c * IN_C + lane];
        float xb1 = x[(size_t)n1c * IN_C + 64 + lane];
        float acc0 = bias, acc1 = bias;
#pragma unroll
        for (int k = 0; k < 64; ++k) {
            float wv = Wt[k * 65 + lane];
            acc0 = fmaf(rl(xa0, k), wv, acc0);
            acc1 = fmaf(rl(xb0, k), wv, acc1);
        }
#pragma unroll
        for (int k = 0; k < 64; ++k) {
            float wv = Wt[(64 + k) * 65 + lane];
            acc0 = fmaf(rl(xa1, k), wv, acc0);
            acc1 = fmaf(rl(xb1, k), wv, acc1);
        }
        h0[(size_t)n0 * HID + lane] = fmaxf(acc0, 0.f);
        if (v1) h0[(size_t)n1 * HID + lane] = fmaxf(acc1, 0.f);
    }
}

// ---- fused GCN2 layer ---------------------------------------------------
// W (already [k][c] layout) staged in LDS; 4 nodes per wave iteration:
// 4 independent gather chains + 4 interleaved GEMM accumulator chains.
__global__ __launch_bounds__(256) void k_layer(const float* __restrict__ hin,
                                               const float* __restrict__ h0,
                                               float* __restrict__ hout,
                                               const float* __restrict__ W,
                                               const int* __restrict__ row_ptr,
                                               const int* __restrict__ col_idx,
                                               float beta, int N) {
    __shared__ float Ws[HID * HID];
    for (int i = threadIdx.x; i < HID * HID; i += 256) Ws[i] = W[i];
    __syncthreads();
    int lane = threadIdx.x & 63;
    int wid = (blockIdx.x * blockDim.x + threadIdx.x) >> 6;
    int nw = (gridDim.x * blockDim.x) >> 6;
    for (int n0 = wid; n0 < N; n0 += 4 * nw) {
        int n1 = n0 + nw, n2 = n0 + 2 * nw, n3 = n0 + 3 * nw;
        bool v1 = n1 < N, v2 = n2 < N, v3 = n3 < N;
        int n1c = v1 ? n1 : n0, n2c = v2 ? n2 : n0, n3c = v3 ? n3 : n0;
        int b0 = row_ptr[n0], d0 = row_ptr[n0 + 1] - b0;
        int b1 = row_ptr[n1c], d1 = v1 ? row_ptr[n1c + 1] - b1 : 0;
        int b2 = row_ptr[n2c], d2 = v2 ? row_ptr[n2c + 1] - b2 : 0;
        int b3 = row_ptr[n3c], d3 = v3 ? row_ptr[n3c + 1] - b3 : 0;
        int dm = max(max(d0, d1), max(d2, d3));
        float a0 = 0.f, a1 = 0.f, a2 = 0.f, a3 = 0.f;
        for (int j = 0; j < dm; ++j) {
            if (j < d0) a0 += hin[(size_t)col_idx[b0 + j] * HID + lane];
            if (j < d1) a1 += hin[(size_t)col_idx[b1 + j] * HID + lane];
            if (j < d2) a2 += hin[(size_t)col_idx[b2 + j] * HID + lane];
            if (j < d3) a3 += hin[(size_t)col_idx[b3 + j] * HID + lane];
        }
        float z0 = 0.9f * a0 + 0.1f * h0[(size_t)n0 * HID + lane];
        float z1 = 0.9f * a1 + 0.1f * h0[(size_t)n1c * HID + lane];
        float z2 = 0.9f * a2 + 0.1f * h0[(size_t)n2c * HID + lane];
        float z3 = 0.9f * a3 + 0.1f * h0[(size_t)n3c * HID + lane];
        float g0 = 0.f, g1 = 0.f, g2 = 0.f, g3 = 0.f;
#pragma unroll
        for (int k = 0; k < HID; ++k) {
            float wv = Ws[k * HID + lane];
            g0 = fmaf(rl(z0, k), wv, g0);
            g1 = fmaf(rl(z1, k), wv, g1);
            g2 = fmaf(rl(z2, k), wv, g2);
            g3 = fmaf(rl(z3, k), wv, g3);
        }
        float ob = 1.f - beta;
        hout[(size_t)n0 * HID + lane] = fmaxf(ob * z0 + beta * g0, 0.f);
        if (v1) hout[(size_t)n1 * HID + lane] = fmaxf(ob * z1 + beta * g1, 0.f);
        if (v2) hout[(size_t)n2 * HID + lane] = fmaxf(ob * z2 + beta * g2, 0.f);
        if (v3) hout[(size_t)n3 * HID + lane] = fmaxf(ob * z3 + beta * g3, 0.f);
    }
}

// ---- output projection: out = h @ lin1_w^T + b --------------------------
__global__ __launch_bounds__(256) void k_lin1(const float* __restrict__ h,
                                              const float* __restrict__ w,
                                              const float* __restrict__ b,
                                              float* __restrict__ out, int N) {
    __shared__ float Wt[HID * 65];
    for (int i = threadIdx.x; i < HID * HID; i += 256) {
        int o = i >> 6, k = i & 63;               // w[o][k]
        Wt[k * 65 + o] = w[i];
    }
    __syncthreads();
    int lane = threadIdx.x & 63;
    int wid = (blockIdx.x * blockDim.x + threadIdx.x) >> 6;
    int nw = (gridDim.x * blockDim.x) >> 6;
    float bias = b[lane];
    for (int n0 = wid; n0 < N; n0 += 2 * nw) {
        int n1 = n0 + nw;
        bool v1 = n1 < N;
        int n1c = v1 ? n1 : n0;
        float ha = h[(size_t)n0 * HID + lane];
        float hb = h[(size_t)n1c * HID + lane];
        float acc0 = bias, acc1 = bias;
#pragma unroll
        for (int k = 0; k < HID; ++k) {
            float wv = Wt[k * 65 + lane];
            acc0 = fmaf(rl(ha, k), wv, acc0);
            acc1 = fmaf(rl(hb, k), wv, acc1);
        }
        out[(size_t)n0 * HID + lane] = acc0;
        if (v1) out[(size_t)n1 * HID + lane] = acc1;
    }
}

extern "C" void kernel_launch(void* const* d_in, const int* in_sizes, int n_in,
                              void* d_out, int out_size, void* d_ws, size_t ws_size,
                              hipStream_t stream) {
    const float* x      = (const float*)d_in[0];
    const int*   ei     = (const int*)d_in[1];
    const float* lin0_w = (const float*)d_in[2];
    const float* lin0_b = (const float*)d_in[3];
    const float* lin1_w = (const float*)d_in[4];
    const float* lin1_b = (const float*)d_in[5];
    const float* conv_w = (const float*)d_in[6];

    int N = in_sizes[0] / IN_C;
    int E = in_sizes[1] / 2;
    const int* src = ei;
    const int* dst = ei + E;

    float* h0 = (float*)d_ws;
    float* hA = h0 + (size_t)N * HID;
    float* hB = hA + (size_t)N * HID;
    int* row_ptr    = (int*)(hB + (size_t)N * HID);
    int* cursor     = row_ptr + (N + 1);
    int* col_idx    = cursor + N;
    int* chunk_sums = col_idx + E;

    int nch = (N + 1023) / 1024;

    // CSR build
    hipMemsetAsync(cursor, 0, (size_t)N * sizeof(int), stream);
    k_hist<<<(E + 255) / 256, 256, 0, stream>>>(dst, cursor, E);
    k_scan_block<<<nch, 1024, 0, stream>>>(cursor, row_ptr, chunk_sums, N);
    k_scan_fix<<<nch, 1024, 0, stream>>>(row_ptr, chunk_sums, N, E);
    hipMemsetAsync(cursor, 0, (size_t)N * sizeof(int), stream);
    k_fill<<<(E + 255) / 256, 256, 0, stream>>>(src, dst, row_ptr, cursor, col_idx, E);

    // input projection -> h0
    k_lin0<<<1024, 256, 0, stream>>>(x, lin0_w, lin0_b, h0, N);

    // 16 fused layers
    const float* cur = h0;
    for (int l = 0; l < 16; ++l) {
        float beta = (float)log(0.5 / (double)(l + 1) + 1.0);
        float* nxt = (l & 1) ? hB : hA;
        k_layer<<<2048, 256, 0, stream>>>(cur, h0, nxt,
                                          conv_w + (size_t)l * HID * HID,
                                          row_ptr, col_idx, beta, N);
        cur = nxt;
    }

    // output projection
    k_lin1<<<1024, 256, 0, stream>>>(cur, lin1_w, lin1_b, (float*)d_out, N);
}

// Round 3
// 1713.688 us; speedup vs baseline: 2.8169x; 2.8169x over previous
//
#include <hip/hip_runtime.h>
#include <cmath>

#define HID 64
#define IN_C 128

__device__ __forceinline__ float rl(float v, int k) {
    return __uint_as_float(__builtin_amdgcn_readlane(__float_as_uint(v), k));
}

struct f4 { float x, y, z, w; };
__device__ __forceinline__ void acc4(f4& a, const f4& b) {
    a.x += b.x; a.y += b.y; a.z += b.z; a.w += b.w;
}

// ---- CSR build ----------------------------------------------------------

__global__ void k_hist(const int* __restrict__ dst, int* __restrict__ counts, int E) {
    int e = blockIdx.x * blockDim.x + threadIdx.x;
    if (e < E) atomicAdd(&counts[dst[e]], 1);
}

__global__ void k_scan_block(const int* __restrict__ counts, int* __restrict__ row_ptr,
                             int* __restrict__ chunk_sums, int n) {
    __shared__ int s[1024];
    int i = blockIdx.x * 1024 + threadIdx.x;
    int v = (i < n) ? counts[i] : 0;
    s[threadIdx.x] = v;
    __syncthreads();
    for (int off = 1; off < 1024; off <<= 1) {
        int t = (threadIdx.x >= off) ? s[threadIdx.x - off] : 0;
        __syncthreads();
        s[threadIdx.x] += t;
        __syncthreads();
    }
    if (i < n) row_ptr[i] = s[threadIdx.x] - v;   // exclusive
    if (threadIdx.x == 1023) chunk_sums[blockIdx.x] = s[1023];
}

__global__ void k_scan_fix(int* __restrict__ row_ptr, const int* __restrict__ chunk_sums,
                           int n, int total) {
    __shared__ int base_s;
    if (threadIdx.x == 0) {
        int b = 0;
        for (int c = 0; c < (int)blockIdx.x; ++c) b += chunk_sums[c];
        base_s = b;
    }
    __syncthreads();
    int i = blockIdx.x * 1024 + threadIdx.x;
    if (i < n) row_ptr[i] += base_s;
    if (i == 0) row_ptr[n] = total;
}

__global__ void k_fill(const int* __restrict__ src, const int* __restrict__ dst,
                       const int* __restrict__ row_ptr, int* __restrict__ cursor,
                       int* __restrict__ col_idx, int E) {
    int e = blockIdx.x * blockDim.x + threadIdx.x;
    if (e < E) {
        int d = dst[e];
        int pos = row_ptr[d] + atomicAdd(&cursor[d], 1);
        col_idx[pos] = src[e];
    }
}

// ---- input projection ----------------------------------------------------
__global__ __launch_bounds__(256) void k_lin0(const float* __restrict__ x,
                                              const float* __restrict__ w,
                                              const float* __restrict__ b,
                                              float* __restrict__ h0, int N) {
    __shared__ float Wt[IN_C * 65];
    for (int i = threadIdx.x; i < IN_C * HID; i += 256) {
        int o = i >> 7, k = i & 127;
        Wt[k * 65 + o] = w[i];
    }
    __syncthreads();
    int lane = threadIdx.x & 63;
    int wid = (blockIdx.x * blockDim.x + threadIdx.x) >> 6;
    int nw = (gridDim.x * blockDim.x) >> 6;
    float bias = b[lane];
    for (int n0 = wid; n0 < N; n0 += 2 * nw) {
        int n1 = n0 + nw;
        bool v1 = n1 < N;
        int n1c = v1 ? n1 : n0;
        float xa0 = x[(size_t)n0 * IN_C + lane];
        float xa1 = x[(size_t)n0 * IN_C + 64 + lane];
        float xb0 = x[(size_t)n1c * IN_C + lane];
        float xb1 = x[(size_t)n1c * IN_C + 64 + lane];
        float acc0 = bias, acc1 = bias;
#pragma unroll
        for (int k = 0; k < 64; ++k) {
            float wv = Wt[k * 65 + lane];
            acc0 = fmaf(rl(xa0, k), wv, acc0);
            acc1 = fmaf(rl(xb0, k), wv, acc1);
        }
#pragma unroll
        for (int k = 0; k < 64; ++k) {
            float wv = Wt[(64 + k) * 65 + lane];
            acc0 = fmaf(rl(xa1, k), wv, acc0);
            acc1 = fmaf(rl(xb1, k), wv, acc1);
        }
        h0[(size_t)n0 * HID + lane] = fmaxf(acc0, 0.f);
        if (v1) h0[(size_t)n1 * HID + lane] = fmaxf(acc1, 0.f);
    }
}

// ---- fused GCN2 layer ----------------------------------------------------
// Wave layout for aggregation: sub = lane>>4 (edge slot), cg = lane&15
// (channel group: channels 4cg..4cg+3 as float4). One dwordx4 instruction
// gathers 4 full rows (1 KB); main loop keeps 8 rows in flight.
__global__ __launch_bounds__(256) void k_layer(const float* __restrict__ hin,
                                               const float* __restrict__ h0,
                                               float* __restrict__ hout,
                                               const float* __restrict__ W,
                                               const int* __restrict__ row_ptr,
                                               const int* __restrict__ col_idx,
                                               float beta, int N) {
    __shared__ float Ws[HID * HID];
    for (int i = threadIdx.x; i < HID * HID; i += 256) Ws[i] = W[i];
    __syncthreads();

    const f4* __restrict__ hin4 = (const f4*)hin;
    const f4* __restrict__ h04 = (const f4*)h0;

    int lane = threadIdx.x & 63;
    int sub = lane >> 4;
    int cg = lane & 15;
    int wid = (blockIdx.x * blockDim.x + threadIdx.x) >> 6;
    int nw = (gridDim.x * blockDim.x) >> 6;

    for (int n = wid; n < N; n += nw) {
        int b = row_ptr[n];
        int d = row_ptr[n + 1] - b;
        f4 a0 = {0.f, 0.f, 0.f, 0.f}, a1 = {0.f, 0.f, 0.f, 0.f};
        int j = 0;
        for (; j + 8 <= d; j += 8) {
            int i0 = col_idx[b + j + sub];
            int i1 = col_idx[b + j + 4 + sub];
            f4 v0 = hin4[(size_t)i0 * 16 + cg];
            f4 v1 = hin4[(size_t)i1 * 16 + cg];
            acc4(a0, v0);
            acc4(a1, v1);
        }
        if (j + sub < d) {
            int i0 = col_idx[b + j + sub];
            acc4(a0, hin4[(size_t)i0 * 16 + cg]);
        }
        if (j + 4 + sub < d) {
            int i1 = col_idx[b + j + 4 + sub];
            acc4(a1, hin4[(size_t)i1 * 16 + cg]);
        }
        acc4(a0, a1);
        // reduce across the 4 edge-slots (all lanes end with full sum)
#pragma unroll
        for (int off = 16; off <= 32; off <<= 1) {
            a0.x += __shfl_xor(a0.x, off);
            a0.y += __shfl_xor(a0.y, off);
            a0.z += __shfl_xor(a0.z, off);
            a0.w += __shfl_xor(a0.w, off);
        }
        f4 hr = h04[(size_t)n * 16 + cg];
        f4 z4;
        z4.x = 0.9f * a0.x + 0.1f * hr.x;
        z4.y = 0.9f * a0.y + 0.1f * hr.y;
        z4.z = 0.9f * a0.z + 0.1f * hr.z;
        z4.w = 0.9f * a0.w + 0.1f * hr.w;

        // GEMM: g_c = sum_k z_k * W[k][c], c = lane
        float g = 0.f;
#pragma unroll
        for (int kg = 0; kg < 16; ++kg) {
            g = fmaf(rl(z4.x, kg), Ws[(4 * kg + 0) * HID + lane], g);
            g = fmaf(rl(z4.y, kg), Ws[(4 * kg + 1) * HID + lane], g);
            g = fmaf(rl(z4.z, kg), Ws[(4 * kg + 2) * HID + lane], g);
            g = fmaf(rl(z4.w, kg), Ws[(4 * kg + 3) * HID + lane], g);
        }
        // z for channel c = lane: component lane&3 of lane (lane>>2)'s z4
        int q = lane >> 2;
        float za = __shfl(z4.x, q), zb = __shfl(z4.y, q);
        float zc = __shfl(z4.z, q), zd = __shfl(z4.w, q);
        int m = lane & 3;
        float zl = (m == 0) ? za : (m == 1) ? zb : (m == 2) ? zc : zd;
        hout[(size_t)n * HID + lane] = fmaxf((1.f - beta) * zl + beta * g, 0.f);
    }
}

// ---- output projection ---------------------------------------------------
__global__ __launch_bounds__(256) void k_lin1(const float* __restrict__ h,
                                              const float* __restrict__ w,
                                              const float* __restrict__ b,
                                              float* __restrict__ out, int N) {
    __shared__ float Wt[HID * 65];
    for (int i = threadIdx.x; i < HID * HID; i += 256) {
        int o = i >> 6, k = i & 63;
        Wt[k * 65 + o] = w[i];
    }
    __syncthreads();
    int lane = threadIdx.x & 63;
    int wid = (blockIdx.x * blockDim.x + threadIdx.x) >> 6;
    int nw = (gridDim.x * blockDim.x) >> 6;
    float bias = b[lane];
    for (int n0 = wid; n0 < N; n0 += 2 * nw) {
        int n1 = n0 + nw;
        bool v1 = n1 < N;
        int n1c = v1 ? n1 : n0;
        float ha = h[(size_t)n0 * HID + lane];
        float hb = h[(size_t)n1c * HID + lane];
        float acc0 = bias, acc1 = bias;
#pragma unroll
        for (int k = 0; k < HID; ++k) {
            float wv = Wt[k * 65 + lane];
            acc0 = fmaf(rl(ha, k), wv, acc0);
            acc1 = fmaf(rl(hb, k), wv, acc1);
        }
        out[(size_t)n0 * HID + lane] = acc0;
        if (v1) out[(size_t)n1 * HID + lane] = acc1;
    }
}

extern "C" void kernel_launch(void* const* d_in, const int* in_sizes, int n_in,
                              void* d_out, int out_size, void* d_ws, size_t ws_size,
                              hipStream_t stream) {
    const float* x      = (const float*)d_in[0];
    const int*   ei     = (const int*)d_in[1];
    const float* lin0_w = (const float*)d_in[2];
    const float* lin0_b = (const float*)d_in[3];
    const float* lin1_w = (const float*)d_in[4];
    const float* lin1_b = (const float*)d_in[5];
    const float* conv_w = (const float*)d_in[6];

    int N = in_sizes[0] / IN_C;
    int E = in_sizes[1] / 2;
    const int* src = ei;
    const int* dst = ei + E;

    float* h0 = (float*)d_ws;
    float* hA = h0 + (size_t)N * HID;
    float* hB = hA + (size_t)N * HID;
    int* row_ptr    = (int*)(hB + (size_t)N * HID);
    int* cursor     = row_ptr + (N + 1);
    int* col_idx    = cursor + N;
    int* chunk_sums = col_idx + E;

    int nch = (N + 1023) / 1024;

    // CSR build
    hipMemsetAsync(cursor, 0, (size_t)N * sizeof(int), stream);
    k_hist<<<(E + 255) / 256, 256, 0, stream>>>(dst, cursor, E);
    k_scan_block<<<nch, 1024, 0, stream>>>(cursor, row_ptr, chunk_sums, N);
    k_scan_fix<<<nch, 1024, 0, stream>>>(row_ptr, chunk_sums, N, E);
    hipMemsetAsync(cursor, 0, (size_t)N * sizeof(int), stream);
    k_fill<<<(E + 255) / 256, 256, 0, stream>>>(src, dst, row_ptr, cursor, col_idx, E);

    // input projection -> h0
    k_lin0<<<1024, 256, 0, stream>>>(x, lin0_w, lin0_b, h0, N);

    // 16 fused layers
    const float* cur = h0;
    for (int l = 0; l < 16; ++l) {
        float beta = (float)log(0.5 / (double)(l + 1) + 1.0);
        float* nxt = (l & 1) ? hB : hA;
        k_layer<<<2048, 256, 0, stream>>>(cur, h0, nxt,
                                          conv_w + (size_t)l * HID * HID,
                                          row_ptr, col_idx, beta, N);
        cur = nxt;
    }

    // output projection
    k_lin1<<<1024, 256, 0, stream>>>(cur, lin1_w, lin1_b, (float*)d_out, N);
}

// Round 4
// 1477.925 us; speedup vs baseline: 3.2663x; 1.1595x over previous
//
#include <hip/hip_runtime.h>
#include <cmath>

#define HID 64
#define IN_C 128

__device__ __forceinline__ float rl(float v, int k) {
    return __uint_as_float(__builtin_amdgcn_readlane(__float_as_uint(v), k));
}
__device__ __forceinline__ float bflo(unsigned u) { return __uint_as_float(u << 16); }
__device__ __forceinline__ float bfhi(unsigned u) { return __uint_as_float(u & 0xffff0000u); }
// pack two floats to bf16 pair with round-to-nearest-even
__device__ __forceinline__ unsigned bfpack(float lo, float hi) {
    unsigned a = __float_as_uint(lo), b = __float_as_uint(hi);
    a = (a + 0x7fffu + ((a >> 16) & 1u)) >> 16;
    b = (b + 0x7fffu + ((b >> 16) & 1u)) & 0xffff0000u;
    return a | b;
}

// ---- CSR build ----------------------------------------------------------

__global__ void k_hist(const int* __restrict__ dst, int* __restrict__ counts, int E) {
    int e = blockIdx.x * blockDim.x + threadIdx.x;
    if (e < E) atomicAdd(&counts[dst[e]], 1);
}

__global__ void k_scan_block(const int* __restrict__ counts, int* __restrict__ row_ptr,
                             int* __restrict__ chunk_sums, int n) {
    __shared__ int s[1024];
    int i = blockIdx.x * 1024 + threadIdx.x;
    int v = (i < n) ? counts[i] : 0;
    s[threadIdx.x] = v;
    __syncthreads();
    for (int off = 1; off < 1024; off <<= 1) {
        int t = (threadIdx.x >= off) ? s[threadIdx.x - off] : 0;
        __syncthreads();
        s[threadIdx.x] += t;
        __syncthreads();
    }
    if (i < n) row_ptr[i] = s[threadIdx.x] - v;   // exclusive
    if (threadIdx.x == 1023) chunk_sums[blockIdx.x] = s[1023];
}

__global__ void k_scan_fix(int* __restrict__ row_ptr, const int* __restrict__ chunk_sums,
                           int n, int total) {
    __shared__ int base_s;
    if (threadIdx.x == 0) {
        int b = 0;
        for (int c = 0; c < (int)blockIdx.x; ++c) b += chunk_sums[c];
        base_s = b;
    }
    __syncthreads();
    int i = blockIdx.x * 1024 + threadIdx.x;
    if (i < n) row_ptr[i] += base_s;
    if (i == 0) row_ptr[n] = total;
}

__global__ void k_fill(const int* __restrict__ src, const int* __restrict__ dst,
                       const int* __restrict__ row_ptr, int* __restrict__ cursor,
                       int* __restrict__ col_idx, int E) {
    int e = blockIdx.x * blockDim.x + threadIdx.x;
    if (e < E) {
        int d = dst[e];
        int pos = row_ptr[d] + atomicAdd(&cursor[d], 1);
        col_idx[pos] = src[e];
    }
}

// ---- input projection: h0(bf16) = relu(x @ lin0_w^T) --------------------
__global__ __launch_bounds__(256) void k_lin0(const float* __restrict__ x,
                                              const float* __restrict__ w,
                                              const float* __restrict__ b,
                                              unsigned* __restrict__ h0, int N) {
    __shared__ float Wt[IN_C * 65];
    for (int i = threadIdx.x; i < IN_C * HID; i += 256) {
        int o = i >> 7, k = i & 127;
        Wt[k * 65 + o] = w[i];
    }
    __syncthreads();
    int lane = threadIdx.x & 63;
    int wid = (blockIdx.x * blockDim.x + threadIdx.x) >> 6;
    int nw = (gridDim.x * blockDim.x) >> 6;
    float bias = b[lane];
    for (int n0 = wid; n0 < N; n0 += 2 * nw) {
        int n1 = n0 + nw;
        bool v1 = n1 < N;
        int n1c = v1 ? n1 : n0;
        float xa0 = x[(size_t)n0 * IN_C + lane];
        float xa1 = x[(size_t)n0 * IN_C + 64 + lane];
        float xb0 = x[(size_t)n1c * IN_C + lane];
        float xb1 = x[(size_t)n1c * IN_C + 64 + lane];
        float acc0 = bias, acc1 = bias;
#pragma unroll
        for (int k = 0; k < 64; ++k) {
            float wv = Wt[k * 65 + lane];
            acc0 = fmaf(rl(xa0, k), wv, acc0);
            acc1 = fmaf(rl(xb0, k), wv, acc1);
        }
#pragma unroll
        for (int k = 0; k < 64; ++k) {
            float wv = Wt[(64 + k) * 65 + lane];
            acc0 = fmaf(rl(xa1, k), wv, acc0);
            acc1 = fmaf(rl(xb1, k), wv, acc1);
        }
        acc0 = fmaxf(acc0, 0.f);
        acc1 = fmaxf(acc1, 0.f);
        // pack channel pairs; even lanes write
        float p0 = __shfl(acc0, lane | 1);
        float p1 = __shfl(acc1, lane | 1);
        if ((lane & 1) == 0) {
            h0[(size_t)n0 * 32 + (lane >> 1)] = bfpack(acc0, p0);
            if (v1) h0[(size_t)n1 * 32 + (lane >> 1)] = bfpack(acc1, p1);
        }
    }
}

// ---- fused GCN2 layer (bf16 state) ---------------------------------------
// Row = 64 bf16 = 128B = 8 x uint4. Lane = (sub = lane>>3 edge slot,
// cg = lane&7 channel group of 8). One dwordx4 fetches 8 rows/wave-instr;
// unroll 2 -> 16 rows in flight.
__global__ __launch_bounds__(256) void k_layer(const uint4* __restrict__ hin,
                                               const uint4* __restrict__ h0,
                                               unsigned* __restrict__ hout,
                                               const float* __restrict__ W,
                                               const int* __restrict__ row_ptr,
                                               const int* __restrict__ col_idx,
                                               float beta, int N) {
    __shared__ float Ws[HID * HID];
    for (int i = threadIdx.x; i < HID * HID; i += 256) Ws[i] = W[i];
    __syncthreads();

    int lane = threadIdx.x & 63;
    int sub = lane >> 3;
    int cg = lane & 7;
    int wid = (blockIdx.x * blockDim.x + threadIdx.x) >> 6;
    int nw = (gridDim.x * blockDim.x) >> 6;

    for (int n = wid; n < N; n += nw) {
        int b = row_ptr[n];
        int d = row_ptr[n + 1] - b;
        float a[8];
#pragma unroll
        for (int c = 0; c < 8; ++c) a[c] = 0.f;
        int j = 0;
        for (; j + 16 <= d; j += 16) {
            int i0 = col_idx[b + j + sub];
            int i1 = col_idx[b + j + 8 + sub];
            uint4 q0 = hin[(size_t)i0 * 8 + cg];
            uint4 q1 = hin[(size_t)i1 * 8 + cg];
            a[0] += bflo(q0.x); a[1] += bfhi(q0.x);
            a[2] += bflo(q0.y); a[3] += bfhi(q0.y);
            a[4] += bflo(q0.z); a[5] += bfhi(q0.z);
            a[6] += bflo(q0.w); a[7] += bfhi(q0.w);
            a[0] += bflo(q1.x); a[1] += bfhi(q1.x);
            a[2] += bflo(q1.y); a[3] += bfhi(q1.y);
            a[4] += bflo(q1.z); a[5] += bfhi(q1.z);
            a[6] += bflo(q1.w); a[7] += bfhi(q1.w);
        }
        if (j + sub < d) {
            int i0 = col_idx[b + j + sub];
            uint4 q0 = hin[(size_t)i0 * 8 + cg];
            a[0] += bflo(q0.x); a[1] += bfhi(q0.x);
            a[2] += bflo(q0.y); a[3] += bfhi(q0.y);
            a[4] += bflo(q0.z); a[5] += bfhi(q0.z);
            a[6] += bflo(q0.w); a[7] += bfhi(q0.w);
        }
        if (j + 8 + sub < d) {
            int i1 = col_idx[b + j + 8 + sub];
            uint4 q1 = hin[(size_t)i1 * 8 + cg];
            a[0] += bflo(q1.x); a[1] += bfhi(q1.x);
            a[2] += bflo(q1.y); a[3] += bfhi(q1.y);
            a[4] += bflo(q1.z); a[5] += bfhi(q1.z);
            a[6] += bflo(q1.w); a[7] += bfhi(q1.w);
        }
        // reduce over the 8 edge slots (bits 3,4,5 of lane)
#pragma unroll
        for (int off = 8; off <= 32; off <<= 1) {
#pragma unroll
            for (int c = 0; c < 8; ++c) a[c] += __shfl_xor(a[c], off);
        }
        // residual
        uint4 hq = h0[(size_t)n * 8 + cg];
        float z[8];
        z[0] = 0.9f * a[0] + 0.1f * bflo(hq.x);
        z[1] = 0.9f * a[1] + 0.1f * bfhi(hq.x);
        z[2] = 0.9f * a[2] + 0.1f * bflo(hq.y);
        z[3] = 0.9f * a[3] + 0.1f * bfhi(hq.y);
        z[4] = 0.9f * a[4] + 0.1f * bflo(hq.z);
        z[5] = 0.9f * a[5] + 0.1f * bfhi(hq.z);
        z[6] = 0.9f * a[6] + 0.1f * bflo(hq.w);
        z[7] = 0.9f * a[7] + 0.1f * bfhi(hq.w);

        // GEMM: channel k = 8*g + c lives on lane g component c
        float g = 0.f;
#pragma unroll
        for (int c = 0; c < 8; ++c) {
#pragma unroll
            for (int gg = 0; gg < 8; ++gg) {
                g = fmaf(rl(z[c], gg), Ws[(8 * gg + c) * HID + lane], g);
            }
        }
        // z for own channel (= lane): component lane&7 from lane (lane>>3)
        int q = lane >> 3;
        float zs[8];
#pragma unroll
        for (int c = 0; c < 8; ++c) zs[c] = __shfl(z[c], q);
        int m = lane & 7;
        float zl = zs[0];
#pragma unroll
        for (int c = 1; c < 8; ++c) zl = (m == c) ? zs[c] : zl;

        float r = fmaxf((1.f - beta) * zl + beta * g, 0.f);
        // pack pairs, even lanes write 4B -> 128B/row
        float rn = __shfl(r, lane | 1);
        if ((lane & 1) == 0) hout[(size_t)n * 32 + (lane >> 1)] = bfpack(r, rn);
    }
}

// ---- output projection: out = h @ lin1_w^T + b --------------------------
__global__ __launch_bounds__(256) void k_lin1(const unsigned* __restrict__ h,
                                              const float* __restrict__ w,
                                              const float* __restrict__ b,
                                              float* __restrict__ out, int N) {
    __shared__ float Wt[HID * 65];
    for (int i = threadIdx.x; i < HID * HID; i += 256) {
        int o = i >> 6, k = i & 63;
        Wt[k * 65 + o] = w[i];
    }
    __syncthreads();
    int lane = threadIdx.x & 63;
    int wid = (blockIdx.x * blockDim.x + threadIdx.x) >> 6;
    int nw = (gridDim.x * blockDim.x) >> 6;
    float bias = b[lane];
    for (int n0 = wid; n0 < N; n0 += 2 * nw) {
        int n1 = n0 + nw;
        bool v1 = n1 < N;
        int n1c = v1 ? n1 : n0;
        unsigned ua = h[(size_t)n0 * 32 + (lane >> 1)];
        unsigned ub = h[(size_t)n1c * 32 + (lane >> 1)];
        float ha = (lane & 1) ? bfhi(ua) : bflo(ua);
        float hb = (lane & 1) ? bfhi(ub) : bflo(ub);
        float acc0 = bias, acc1 = bias;
#pragma unroll
        for (int k = 0; k < 64; ++k) {
            float wv = Wt[k * 65 + lane];
            acc0 = fmaf(rl(ha, k), wv, acc0);
            acc1 = fmaf(rl(hb, k), wv, acc1);
        }
        out[(size_t)n0 * HID + lane] = acc0;
        if (v1) out[(size_t)n1 * HID + lane] = acc1;
    }
}

extern "C" void kernel_launch(void* const* d_in, const int* in_sizes, int n_in,
                              void* d_out, int out_size, void* d_ws, size_t ws_size,
                              hipStream_t stream) {
    const float* x      = (const float*)d_in[0];
    const int*   ei     = (const int*)d_in[1];
    const float* lin0_w = (const float*)d_in[2];
    const float* lin0_b = (const float*)d_in[3];
    const float* lin1_w = (const float*)d_in[4];
    const float* lin1_b = (const float*)d_in[5];
    const float* conv_w = (const float*)d_in[6];

    int N = in_sizes[0] / IN_C;
    int E = in_sizes[1] / 2;
    const int* src = ei;
    const int* dst = ei + E;

    // bf16 state buffers: N*64*2B = N*32 uints each
    unsigned* h0 = (unsigned*)d_ws;
    unsigned* hA = h0 + (size_t)N * 32;
    unsigned* hB = hA + (size_t)N * 32;
    int* row_ptr    = (int*)(hB + (size_t)N * 32);
    int* cursor     = row_ptr + (N + 1);
    int* col_idx    = cursor + N;
    int* chunk_sums = col_idx + E;

    int nch = (N + 1023) / 1024;

    // CSR build
    hipMemsetAsync(cursor, 0, (size_t)N * sizeof(int), stream);
    k_hist<<<(E + 255) / 256, 256, 0, stream>>>(dst, cursor, E);
    k_scan_block<<<nch, 1024, 0, stream>>>(cursor, row_ptr, chunk_sums, N);
    k_scan_fix<<<nch, 1024, 0, stream>>>(row_ptr, chunk_sums, N, E);
    hipMemsetAsync(cursor, 0, (size_t)N * sizeof(int), stream);
    k_fill<<<(E + 255) / 256, 256, 0, stream>>>(src, dst, row_ptr, cursor, col_idx, E);

    // input projection -> h0 (bf16)
    k_lin0<<<1024, 256, 0, stream>>>(x, lin0_w, lin0_b, h0, N);

    // 16 fused layers
    const unsigned* cur = h0;
    for (int l = 0; l < 16; ++l) {
        float beta = (float)log(0.5 / (double)(l + 1) + 1.0);
        unsigned* nxt = (l & 1) ? hB : hA;
        k_layer<<<2048, 256, 0, stream>>>((const uint4*)cur, (const uint4*)h0, nxt,
                                          conv_w + (size_t)l * HID * HID,
                                          row_ptr, col_idx, beta, N);
        cur = nxt;
    }

    // output projection
    k_lin1<<<1024, 256, 0, stream>>>(cur, lin1_w, lin1_b, (float*)d_out, N);
}